// Round 7
// baseline (1647.397 us; speedup 1.0000x reference)
//
#include <hip/hip_runtime.h>

#define NCOLS   8
#define BLOCK   256
#define NB      512         // streaming blocks for hist/scatter
#define NBKT    1024        // row buckets (one accum block each)
#define LG2RPB  10
#define RPB     1024        // rows per bucket
#define NCHUNK  16          // chunks for the transpose-scan
#define CB      (NB / NCHUNK)
#define NSLICE  8           // col slices (field slice = 4 MB -> fits XCD L2)
#define SORTCAP 19456       // max records/bucket for LDS slice-sort (152 KB)

// ---------- index-width autodetect (int32 vs int64 COO indices) ----------
// All index values < 2^20, so int64 data has zero high words. P(false pos) ~ 1e-96.
__device__ __forceinline__ int detect_is64(const void* p) {
    const unsigned* w = (const unsigned*)p;
    int is64 = 1;
    #pragma unroll
    for (int k = 0; k < 16; ++k) is64 &= (w[2 * k + 1] == 0u) ? 1 : 0;
    return is64;
}

__device__ __forceinline__ int load_idx(const void* p, int i, int is64) {
    return is64 ? (int)((const long long*)p)[i] : ((const int*)p)[i];
}

// ---------- k1: per-block row-bucket histogram ----------
__global__ __launch_bounds__(BLOCK) void k_hist(
    const void* __restrict__ rowp, int nnz, int chunk, unsigned* __restrict__ hist)
{
    __shared__ unsigned h[NBKT];
    const int is64 = detect_is64(rowp);
    for (int i = threadIdx.x; i < NBKT; i += BLOCK) h[i] = 0u;
    __syncthreads();
    const int beg = blockIdx.x * chunk;
    const int end = min(nnz, beg + chunk);
    for (int i = beg + threadIdx.x; i < end; i += BLOCK)
        atomicAdd(&h[load_idx(rowp, i, is64) >> LG2RPB], 1u);
    __syncthreads();
    unsigned* row = hist + (size_t)blockIdx.x * NBKT;
    for (int i = threadIdx.x; i < NBKT; i += BLOCK) row[i] = h[i];
}

// ---------- k2a: partial sums per (chunk, bucket) ----------
__global__ __launch_bounds__(BLOCK) void k_partial(
    const unsigned* __restrict__ hist, unsigned* __restrict__ partial)
{
    const int t = blockIdx.x * BLOCK + threadIdx.x;     // [0, NCHUNK*NBKT)
    const int c = t >> 10, k = t & (NBKT - 1);
    unsigned s = 0;
    #pragma unroll 4
    for (int j = 0; j < CB; ++j) s += hist[(size_t)(c * CB + j) * NBKT + k];
    partial[(size_t)c * NBKT + k] = s;
}

// ---------- k2b: bucket totals + global scan + chunk bases ----------
__global__ __launch_bounds__(NBKT) void k_scan(
    unsigned* __restrict__ partial, unsigned* __restrict__ base)
{
    __shared__ unsigned s[NBKT];
    const int k = threadIdx.x;
    unsigned tot = 0;
    #pragma unroll
    for (int c = 0; c < NCHUNK; ++c) tot += partial[(size_t)c * NBKT + k];
    s[k] = tot;
    __syncthreads();
    for (int off = 1; off < NBKT; off <<= 1) {
        unsigned v = (k >= off) ? s[k - off] : 0u;
        __syncthreads();
        s[k] += v;
        __syncthreads();
    }
    unsigned run = s[k] - tot;                          // exclusive bucket base
    base[k] = run;
    if (k == NBKT - 1) base[NBKT] = s[k];
    #pragma unroll
    for (int c = 0; c < NCHUNK; ++c) {
        unsigned t = partial[(size_t)c * NBKT + k];
        partial[(size_t)c * NBKT + k] = run;
        run += t;
    }
}

// ---------- k2c: apply — per-block global write bases ----------
__global__ __launch_bounds__(BLOCK) void k_apply(
    unsigned* __restrict__ hist, const unsigned* __restrict__ partial)
{
    const int t = blockIdx.x * BLOCK + threadIdx.x;
    const int c = t >> 10, k = t & (NBKT - 1);
    unsigned run = partial[(size_t)c * NBKT + k];
    #pragma unroll 4
    for (int j = 0; j < CB; ++j) {
        const size_t idx = (size_t)(c * CB + j) * NBKT + k;
        unsigned v = hist[idx];
        hist[idx] = run;
        run += v;
    }
}

// ---------- k3: scatter into bucket-grouped order (LDS cursors) ----------
// record = (localrow<<20 | col, bits(val)), 8 bytes
__global__ __launch_bounds__(BLOCK) void k_scatter(
    const float* __restrict__ vals, const void* __restrict__ rowp,
    const void* __restrict__ colp, int nnz, int chunk,
    const unsigned* __restrict__ hist, uint2* __restrict__ records)
{
    __shared__ unsigned cur[NBKT];
    const int is64 = detect_is64(rowp);
    const unsigned* wb = hist + (size_t)blockIdx.x * NBKT;
    for (int i = threadIdx.x; i < NBKT; i += BLOCK) cur[i] = wb[i];
    __syncthreads();
    const int beg = blockIdx.x * chunk;
    const int end = min(nnz, beg + chunk);
    for (int i = beg + threadIdx.x; i < end; i += BLOCK) {
        int r = load_idx(rowp, i, is64);
        int c = load_idx(colp, i, is64);
        float v = vals[i];
        unsigned pos = atomicAdd(&cur[r >> LG2RPB], 1u);
        records[pos] = make_uint2((((unsigned)r & (RPB - 1u)) << 20) | (unsigned)c,
                                  __float_as_uint(v));
    }
}

// ---------- k4: in-place per-bucket counting sort by col-slice (LDS, atomic-free) ----------
__global__ __launch_bounds__(BLOCK) void k_slicesort(
    uint2* __restrict__ records, const unsigned* __restrict__ base,
    unsigned* __restrict__ boff, int lg2spl)
{
    __shared__ uint2 buf[SORTCAP];                      // 152 KB
    __shared__ unsigned short cnt[BLOCK][NSLICE];       // 4 KB
    __shared__ unsigned sbase[NSLICE + 1];
    const int b = blockIdx.x, t = threadIdx.x;
    const unsigned beg = base[b], end = base[b + 1], m = end - beg;

    if (m > SORTCAP) {
        // oversize (extreme skew): leave unsorted; slice 0 processes everything
        if (t < NSLICE) boff[b * NSLICE + t] = t ? end : beg;
        return;
    }

    // pass A: per-thread slice counts (strided-coalesced read)
    unsigned short c[NSLICE];
    #pragma unroll
    for (int s = 0; s < NSLICE; ++s) c[s] = 0;
    for (unsigned i = t; i < m; i += BLOCK)
        c[(records[beg + i].x & 0xFFFFFu) >> lg2spl]++;
    #pragma unroll
    for (int s = 0; s < NSLICE; ++s) cnt[t][s] = c[s];
    __syncthreads();

    // pass B: rank scan across threads per slice (deterministic, no atomics)
    if (t < NSLICE) {
        unsigned run = 0;
        for (int k = 0; k < BLOCK; ++k) {
            unsigned v = cnt[k][t];
            cnt[k][t] = (unsigned short)run;
            run += v;
        }
        sbase[t] = run;                                 // slice total (temp)
    }
    __syncthreads();
    if (t == 0) {
        unsigned run = 0;
        #pragma unroll
        for (int s = 0; s < NSLICE; ++s) { unsigned v = sbase[s]; sbase[s] = run; run += v; }
        sbase[NSLICE] = run;                            // == m
    }
    __syncthreads();
    if (t < NSLICE) boff[b * NSLICE + t] = beg + sbase[t];

    // pass C: place records into LDS at sorted positions (reads hit L2)
    unsigned cur[NSLICE];
    #pragma unroll
    for (int s = 0; s < NSLICE; ++s) cur[s] = sbase[s] + cnt[t][s];
    for (unsigned i = t; i < m; i += BLOCK) {
        uint2 r = records[beg + i];
        unsigned s = (r.x & 0xFFFFFu) >> lg2spl;
        buf[cur[s]++] = r;
    }
    __syncthreads();

    // pass D: coalesced in-place writeback
    for (unsigned i = t; i < m; i += BLOCK) records[beg + i] = buf[i];
}

// ---------- k5 (x NSLICE launches): slice-resident gather + LDS accumulate ----------
__global__ __launch_bounds__(BLOCK) void k_accum_s(
    const uint2* __restrict__ records, const unsigned* __restrict__ boff,
    const unsigned* __restrict__ base, const float* __restrict__ field,
    float* __restrict__ out, int n, int s)
{
    __shared__ float acc[NCOLS * RPB];                  // 32 KB, transposed acc[j*RPB+lr]
    const int b = blockIdx.x;
    const size_t row0 = (size_t)b * RPB;

    if (s == 0) {
        for (int i = threadIdx.x; i < NCOLS * RPB; i += BLOCK) acc[i] = 0.f;
    } else {
        for (int t = threadIdx.x; t < NCOLS * RPB; t += BLOCK) {
            int r = t >> 3, j = t & 7;
            size_t gr = row0 + (size_t)r;
            acc[j * RPB + r] = (gr < (size_t)n) ? out[gr * NCOLS + j] : 0.f;
        }
    }
    __syncthreads();

    const unsigned sbeg = boff[b * NSLICE + s];
    const unsigned send = (s < NSLICE - 1) ? boff[b * NSLICE + s + 1] : base[b + 1];
    for (unsigned i = sbeg + threadIdx.x; i < send; i += BLOCK) {
        const uint2 rec = records[i];
        const unsigned col = rec.x & 0xFFFFFu;
        const unsigned lr  = rec.x >> 20;
        const float v = __uint_as_float(rec.y);
        const float4* f = (const float4*)(field + (size_t)col * NCOLS);
        const float4 f0 = f[0], f1 = f[1];
        atomicAdd(&acc[0 * RPB + lr], v * f0.x);
        atomicAdd(&acc[1 * RPB + lr], v * f0.y);
        atomicAdd(&acc[2 * RPB + lr], v * f0.z);
        atomicAdd(&acc[3 * RPB + lr], v * f0.w);
        atomicAdd(&acc[4 * RPB + lr], v * f1.x);
        atomicAdd(&acc[5 * RPB + lr], v * f1.y);
        atomicAdd(&acc[6 * RPB + lr], v * f1.z);
        atomicAdd(&acc[7 * RPB + lr], v * f1.w);
    }
    __syncthreads();

    for (int t = threadIdx.x; t < NCOLS * RPB; t += BLOCK) {
        int r = t >> 3, j = t & 7;
        size_t gr = row0 + (size_t)r;
        if (gr < (size_t)n) out[gr * NCOLS + j] = acc[j * RPB + r];
    }
}

// ---------- fallback: direct atomic scatter ----------
__global__ __launch_bounds__(BLOCK) void lap_zero_kernel(float4* __restrict__ out, int n4) {
    int i = blockIdx.x * BLOCK + threadIdx.x;
    if (i < n4) out[i] = make_float4(0.f, 0.f, 0.f, 0.f);
}

__global__ __launch_bounds__(BLOCK) void lap_spmm_atomic(
    const float* __restrict__ vals, const void* __restrict__ rowp,
    const void* __restrict__ colp, const float* __restrict__ field,
    float* __restrict__ out, int nnz)
{
    const int is64 = detect_is64(rowp);
    int i = blockIdx.x * BLOCK + threadIdx.x;
    if (i >= nnz) return;
    float v = vals[i];
    int r = load_idx(rowp, i, is64);
    int c = load_idx(colp, i, is64);
    const float4* f = (const float4*)(field + (size_t)c * NCOLS);
    float4 f0 = f[0], f1 = f[1];
    float* o = out + (size_t)r * NCOLS;
    unsafeAtomicAdd(o + 0, v * f0.x);
    unsafeAtomicAdd(o + 1, v * f0.y);
    unsafeAtomicAdd(o + 2, v * f0.z);
    unsafeAtomicAdd(o + 3, v * f0.w);
    unsafeAtomicAdd(o + 4, v * f1.x);
    unsafeAtomicAdd(o + 5, v * f1.y);
    unsafeAtomicAdd(o + 6, v * f1.z);
    unsafeAtomicAdd(o + 7, v * f1.w);
}

extern "C" void kernel_launch(void* const* d_in, const int* in_sizes, int n_in,
                              void* d_out, int out_size, void* d_ws, size_t ws_size,
                              hipStream_t stream) {
    const float* field = (const float*)d_in[0];
    const float* vals  = (const float*)d_in[1];
    const void*  rowp  = d_in[2];
    const void*  colp  = d_in[3];
    float* out = (float*)d_out;

    const int nnz = in_sizes[1];
    const int n   = out_size / NCOLS;
    char* ws = (char*)d_ws;

    // ws layout (boff aliases the hist region — hist is dead after k_scatter)
    const size_t o_hist    = 0;                                     // NB*NBKT u32 = 2 MB
    const size_t o_partial = o_hist + (size_t)NB * NBKT * 4;        // NCHUNK*NBKT u32
    const size_t o_base    = o_partial + (size_t)NCHUNK * NBKT * 4; // NBKT+1 u32
    const size_t o_rec     = (o_base + (size_t)(NBKT + 1) * 4 + 255) & ~(size_t)255;
    const size_t need      = o_rec + (size_t)nnz * 8;

    if (n <= NBKT * RPB && n <= (1 << 20) && ws_size >= need) {
        unsigned* hist    = (unsigned*)(ws + o_hist);
        unsigned* boff    = (unsigned*)(ws + o_hist);   // alias (NSLICE*NBKT u32 = 32 KB)
        unsigned* partial = (unsigned*)(ws + o_partial);
        unsigned* base    = (unsigned*)(ws + o_base);
        uint2*    rec     = (uint2*)(ws + o_rec);

        const int chunk = (nnz + NB - 1) / NB;

        // slice width: ceil_log2(n) - 3  =>  <= 8 slices, slice <= n/8 rows of field
        int lg = 0;
        while ((1u << lg) < (unsigned)n) ++lg;
        const int lg2spl = lg > 3 ? lg - 3 : 0;

        k_hist<<<NB, BLOCK, 0, stream>>>(rowp, nnz, chunk, hist);
        k_partial<<<NCHUNK * NBKT / BLOCK, BLOCK, 0, stream>>>(hist, partial);
        k_scan<<<1, NBKT, 0, stream>>>(partial, base);
        k_apply<<<NCHUNK * NBKT / BLOCK, BLOCK, 0, stream>>>(hist, partial);
        k_scatter<<<NB, BLOCK, 0, stream>>>(vals, rowp, colp, nnz, chunk, hist, rec);
        k_slicesort<<<NBKT, BLOCK, 0, stream>>>(rec, base, boff, lg2spl);
        for (int s = 0; s < NSLICE; ++s)
            k_accum_s<<<NBKT, BLOCK, 0, stream>>>(rec, boff, base, field, out, n, s);
        return;
    }

    // fallback
    const int n4 = out_size / 4;
    lap_zero_kernel<<<(n4 + BLOCK - 1) / BLOCK, BLOCK, 0, stream>>>((float4*)out, n4);
    lap_spmm_atomic<<<(nnz + BLOCK - 1) / BLOCK, BLOCK, 0, stream>>>(
        vals, rowp, colp, field, out, nnz);
}